// Round 3
// baseline (753.246 us; speedup 1.0000x reference)
//
#include <hip/hip_runtime.h>

// est[bc][f][w] = dot(A[bc][f][:], B[w][:]);  out[bc][8f+i] = est[f][i] + est[f-1][8+i]
// A: [16][16000][512] fp32 (524 MB HBM stream), B: [16][512] fp32 held in VGPRs,
// out: [16][128008] fp32.
//
// One 64-lane wave per workgroup, per 128 output frames. Lane split:
//   wq = l&7  -> w in {2wq, 2wq+1};  ksl = l>>3 -> k in [ksl*64, ksl*64+64)
// B regs: 2w x 64k = 128 VGPR/lane (whole wave holds all of B).
// A path: fully-coalesced global loads (2 x dwordx4 = 2KB row) -> VGPR ->
// XOR-swizzled LDS ping-pong -> conflict-free ds_read_b128 per-lane k-slices.
// Reduction over the 8 ksl groups: 3 x shfl_xor. Overlap-add via a 16-frame
// LDS ring, epilogue every 8 frames writes 64 contiguous floats.

#define FRAMES 16000
#define OUT_PER_BC 128008          // 8 * 16001
#define OFPW 128                   // output frames per wave

__global__ __launch_bounds__(64, 2)
void decoder_kernel(const float* __restrict__ A,
                    const float* __restrict__ B,
                    float* __restrict__ out)
{
    __shared__ float4 Aslot[2][128];   // 2 x 2KB frame slots (swizzled)
    __shared__ float  ring[16][16];    // est ring [frame&15][w]

    const int l   = threadIdx.x;       // 0..63
    const int wq  = l & 7;
    const int ksl = l >> 3;
    const int bc  = blockIdx.y;
    const int o0  = blockIdx.x * OFPW; // even

    // ---- B into registers: Bw?[j] = B[2wq+?][ksl*64 + 4j .. 4j+3]
    const float4* B4 = (const float4*)B;
    float4 Bw0[16], Bw1[16];
    #pragma unroll
    for (int j = 0; j < 16; ++j) {
        Bw0[j] = B4[(2*wq    ) * 128 + ksl*16 + j];
        Bw1[j] = B4[(2*wq + 1) * 128 + ksl*16 + j];
    }

    const float4* Abc = (const float4*)A + (size_t)bc * FRAMES * 128;

    // XOR-swizzle: logical float4 idx L -> phys L ^ ((L>>4)&7). Involution;
    // read pattern ksl*16+j -> phys ksl*16+(j^ksl): 8 unique addrs hit 8
    // distinct bank-quads (conflict-free); write pattern stays linear-grade.
    const int p0 = l ^ (l >> 4);                      // phys for logical l
    const int p1 = 64 + (l ^ ((4 + (l >> 4)) & 7));   // phys for logical 64+l

    float4 V[2][2];   // staging regs: V[frame&1][half]

    auto ldA = [&](int par, int f) {
        int fc = f < 0 ? 0 : (f >= FRAMES ? FRAMES - 1 : f);  // clamp (ghosts zeroed later)
        const float4* p = Abc + (size_t)fc * 128;
        V[par][0] = p[l];        // fully coalesced 1KB
        V[par][1] = p[64 + l];   // fully coalesced 1KB
    };
    auto stA = [&](int par) {
        Aslot[par][p0] = V[par][0];
        Aslot[par][p1] = V[par][1];
    };
    auto epilogue = [&](int fb) {     // outputs for frames [fb, fb+8)
        const int fr = fb + (l >> 3);
        const float v = ring[fr & 15][l & 7] + ring[(fr - 1) & 15][8 + (l & 7)];
        if (fr <= FRAMES)
            out[(size_t)bc * OUT_PER_BC + (size_t)fb * 8 + l] = v;
    };
    auto compute = [&](int f, int s) { // s = f&1 (compile-time after unroll)
        float a00 = 0.f, a01 = 0.f, a10 = 0.f, a11 = 0.f;
        #pragma unroll
        for (int j = 0; j < 16; ++j) {
            const float4 a  = Aslot[s][ksl*16 + (j ^ ksl)];
            const float4 b0 = Bw0[j];
            const float4 b1 = Bw1[j];
            if (j & 1) {
                a01 = fmaf(a.x, b0.x, a01); a01 = fmaf(a.y, b0.y, a01);
                a01 = fmaf(a.z, b0.z, a01); a01 = fmaf(a.w, b0.w, a01);
                a11 = fmaf(a.x, b1.x, a11); a11 = fmaf(a.y, b1.y, a11);
                a11 = fmaf(a.z, b1.z, a11); a11 = fmaf(a.w, b1.w, a11);
            } else {
                a00 = fmaf(a.x, b0.x, a00); a00 = fmaf(a.y, b0.y, a00);
                a00 = fmaf(a.z, b0.z, a00); a00 = fmaf(a.w, b0.w, a00);
                a10 = fmaf(a.x, b1.x, a10); a10 = fmaf(a.y, b1.y, a10);
                a10 = fmaf(a.z, b1.z, a10); a10 = fmaf(a.w, b1.w, a10);
            }
        }
        float r0 = a00 + a01;
        float r1 = a10 + a11;
        r0 += __shfl_xor(r0, 8);   r1 += __shfl_xor(r1, 8);   // reduce over ksl
        r0 += __shfl_xor(r0, 16);  r1 += __shfl_xor(r1, 16);
        r0 += __shfl_xor(r0, 32);  r1 += __shfl_xor(r1, 32);
        if (f < 0 || f >= FRAMES) { r0 = 0.f; r1 = 0.f; }     // ghost frames
        if (ksl == 0) {
            ring[f & 15][2*wq    ] = r0;
            ring[f & 15][2*wq + 1] = r1;
        }
    };

    // ---- pipeline prologue: iteration f = o0-1 (parity 1) ----
    ldA(1, o0 - 1);
    ldA(0, o0);
    stA(1);                 // waits o0-1 loads; o0 still in flight
    __syncthreads();
    ldA(1, o0 + 1);
    compute(o0 - 1, 1);     // est[o0-1] into ring (redundant w/ prev wave; ghost-safe)

    // ---- main loop: invariant at f: V[f&1]=frame f, V[(f+1)&1]=f+1 in flight
    for (int b = 0; b < 16; ++b) {
        #pragma unroll
        for (int r = 0; r < 8; ++r) {
            const int f   = o0 + b * 8 + r;
            const int par = r & 1;             // == f&1 (o0, b*8 even)
            stA(par);                          // frame f -> LDS slot
            __syncthreads();
            if (r == 0 && b > 0) epilogue(f - 8);
            ldA(par, f + 2);                   // deep prefetch, post-barrier
            compute(f, par);
        }
    }
    __syncthreads();
    epilogue(o0 + 120);     // final batch
}

extern "C" void kernel_launch(void* const* d_in, const int* in_sizes, int n_in,
                              void* d_out, int out_size, void* d_ws, size_t ws_size,
                              hipStream_t stream) {
    const float* A   = (const float*)d_in[0];   // mixture_w [16][16000][512]
    const float* B   = (const float*)d_in[1];   // basis_weight [16][512]
    float*       out = (float*)d_out;           // [16][128008]

    // 126 waves per bc x 128 frames covers 16001 output frames; 2016 waves total
    dim3 grid(126, 16, 1);
    decoder_kernel<<<grid, dim3(64, 1, 1), 0, stream>>>(A, B, out);
}